// Round 18
// baseline (700.287 us; speedup 1.0000x reference)
//
#include <hip/hip_runtime.h>
#include <hip/hip_bf16.h>
#include <cmath>

#define N_NODES 20000
#define FF 78
#define F3 234   // 3*78
#define F4 312   // 4*78
#define NRBF 20
#define CUTOFF 21.0f
#define NL 3
#define PI_F 3.14159265358979323846f
#define EPS_F 1e-15f
#define REC_STRIDE 24
#define CHUNK 64
#define UV_RN 16  // nodes per block in k_upd_uv

typedef float f2 __attribute__((ext_vector_type(2)));
static __device__ __forceinline__ f2 mkf2(float a, float b) { f2 r; r.x = a; r.y = b; return r; }
#if defined(__has_builtin)
# if __has_builtin(__builtin_elementwise_fma)
#  define FMA2(a,b,c) __builtin_elementwise_fma((a),(b),(c))
# endif
#endif
#ifndef FMA2
static __device__ __forceinline__ f2 fma2_(f2 a, f2 b, f2 c) {
    f2 r; r.x = fmaf(a.x, b.x, c.x); r.y = fmaf(a.y, b.y, c.y); return r;
}
# define FMA2(a,b,c) fma2_((a),(b),(c))
#endif

// ---------------- init: zero counts/cursor only (H handled by l0 kernels) ----------------
__global__ void k_init(int* __restrict__ counts, int* __restrict__ cursor)
{
    int idx = blockIdx.x * blockDim.x + threadIdx.x;
    if (idx < N_NODES) { counts[idx] = 0; cursor[idx] = 0; }
}

// ---------------- active-edge degree count (geometry recomputed in k_fill) ----------------
__global__ void k_geo(const float* __restrict__ xyz, const int* __restrict__ nbr,
                      int* __restrict__ counts, int E)
{
    int e = blockIdx.x * blockDim.x + threadIdx.x;
    if (e >= E) return;
    int i = nbr[2 * e], j = nbr[2 * e + 1];
    float rx = xyz[3 * j]     - xyz[3 * i];
    float ry = xyz[3 * j + 1] - xyz[3 * i + 1];
    float rz = xyz[3 * j + 2] - xyz[3 * i + 2];
    float d = sqrtf(rx * rx + ry * ry + rz * rz + 3.0f * EPS_F);
    if (d < CUTOFF) atomicAdd(&counts[i], 1);   // env==0 edges contribute exactly nothing
}

// ---------------- exclusive scan of counts -> row_start (single block, 1024 thr) ----------------
__global__ __launch_bounds__(1024)
void k_scan(const int* __restrict__ counts, int* __restrict__ row_start, int n)
{
    __shared__ int s[1024];
    const int t = threadIdx.x;
    constexpr int PER = 20;                 // 1024*20 = 20480 >= n+1
    const int base = t * PER;
    int loc[PER];
    int sum = 0;
    #pragma unroll
    for (int q = 0; q < PER; ++q) {
        int idx = base + q;
        int v = (idx < n) ? counts[idx] : 0;
        loc[q] = sum;
        sum += v;
    }
    s[t] = sum;
    __syncthreads();
    for (int off = 1; off < 1024; off <<= 1) {
        int add = (t >= off) ? s[t - off] : 0;
        __syncthreads();
        s[t] += add;
        __syncthreads();
    }
    const int excl = (t > 0) ? s[t - 1] : 0;
    #pragma unroll
    for (int q = 0; q < PER; ++q) {
        int idx = base + q;
        if (idx <= n) row_start[idx] = excl + loc[q];
    }
}

// ---------------- fill CSR + edge record in one pass (Chebyshev sin recurrence) ----------------
__global__ void k_fill(const float* __restrict__ xyz, const int* __restrict__ nbr,
                       const int* __restrict__ row_start, int* __restrict__ cursor,
                       float* __restrict__ rec, int* __restrict__ jl, int E)
{
    int e = blockIdx.x * blockDim.x + threadIdx.x;
    if (e >= E) return;
    int i = nbr[2 * e], j = nbr[2 * e + 1];
    float rx = xyz[3 * j]     - xyz[3 * i];
    float ry = xyz[3 * j + 1] - xyz[3 * i + 1];
    float rz = xyz[3 * j + 2] - xyz[3 * i + 2];
    float d = sqrtf(rx * rx + ry * ry + rz * rz + 3.0f * EPS_F);
    if (d < CUTOFF) {
        int pos = row_start[i] + atomicAdd(&cursor[i], 1);
        float theta = PI_F * d / CUTOFF;
        float s1, c1;
        sincosf(theta, &s1, &c1);
        float env = 0.5f * (c1 + 1.0f);
        float envd = env / d;
        float inv_d = 1.f / d;
        float* r = rec + (size_t)pos * REC_STRIDE;
        float twoc = 2.f * c1;
        float skm = 0.f, sk = s1;
        r[0] = envd * sk;
        #pragma unroll
        for (int k = 1; k < NRBF; ++k) {
            float sk1 = twoc * sk - skm;
            r[k] = envd * sk1;
            skm = sk; sk = sk1;
        }
        r[20] = env;
        r[21] = rx * inv_d; r[22] = ry * inv_d; r[23] = rz * inv_d;
        jl[pos] = j;
    }
}

// ---------------- fused 2-layer MLP (message): phi = silu(H@w1+b1)@w2+b2 -> bf16 ----------------
template<int K1T, int K2T, int NC2, int CS2, int BF16OUT>
__global__ void k_mlp2(const float* __restrict__ X1, const float* __restrict__ X2,
                       const float* __restrict__ w1, const float* __restrict__ b1,
                       const float* __restrict__ w2, const float* __restrict__ b2,
                       void* __restrict__ Yv, int nrows)
{
    constexpr int R = 32;
    constexpr int K = K1T + K2T;
    __shared__ float sX[K * R];
    __shared__ float s2[78 * 33];
    const int r0 = blockIdx.x * R;
    const int tid = threadIdx.y * 78 + threadIdx.x;
    for (int idx = tid; idx < R * K; idx += 312) {
        int r = idx / K, k = idx - r * K;
        int row = r0 + r;
        float v = 0.f;
        if (row < nrows) {
            if constexpr (K2T == 0) v = X1[(size_t)row * K1T + k];
            else v = (k < K1T) ? X1[(size_t)row * K1T + k] : X2[(size_t)row * K2T + (k - K1T)];
        }
        sX[k * R + r] = v;
    }
    __syncthreads();
    const int rg = threadIdx.y * 8;
    // phase 1: hid = silu(X@w1+b1)  (explicit b128 LDS reads, conflict-free broadcast)
    {
        const int c = threadIdx.x;
        float acc[8];
        #pragma unroll
        for (int q = 0; q < 8; ++q) acc[q] = 0.f;
        for (int k = 0; k < K; ++k) {
            const float w = w1[k * 78 + c];
            const float4 xa = *(const float4*)&sX[k * R + rg];
            const float4 xb = *(const float4*)&sX[k * R + rg + 4];
            acc[0] = fmaf(w, xa.x, acc[0]); acc[1] = fmaf(w, xa.y, acc[1]);
            acc[2] = fmaf(w, xa.z, acc[2]); acc[3] = fmaf(w, xa.w, acc[3]);
            acc[4] = fmaf(w, xb.x, acc[4]); acc[5] = fmaf(w, xb.y, acc[5]);
            acc[6] = fmaf(w, xb.z, acc[6]); acc[7] = fmaf(w, xb.w, acc[7]);
        }
        const float bb = b1[c];
        #pragma unroll
        for (int q = 0; q < 8; ++q) {
            float y = acc[q] + bb;
            y = y / (1.f + expf(-y));
            s2[c * 33 + rg + q] = y;
        }
    }
    __syncthreads();
    // phase 2: Y = hid@w2+b2
    {
        const int c0 = threadIdx.x * CS2;
        float acc[8][CS2];
        #pragma unroll
        for (int q = 0; q < 8; ++q)
            #pragma unroll
            for (int cc = 0; cc < CS2; ++cc) acc[q][cc] = 0.f;
        for (int k = 0; k < 78; ++k) {
            float xv[8];
            #pragma unroll
            for (int q = 0; q < 8; ++q) xv[q] = s2[k * 33 + rg + q];
            float wv[CS2];
            #pragma unroll
            for (int cc = 0; cc < CS2; ++cc) wv[cc] = w2[(size_t)k * NC2 + c0 + cc];
            #pragma unroll
            for (int q = 0; q < 8; ++q)
                #pragma unroll
                for (int cc = 0; cc < CS2; ++cc) acc[q][cc] = fmaf(xv[q], wv[cc], acc[q][cc]);
        }
        #pragma unroll
        for (int q = 0; q < 8; ++q) {
            int row = r0 + rg + q;
            if (row < nrows) {
                if constexpr (BF16OUT && CS2 == 4) {
                    union { __hip_bfloat16 hh[4]; uint2 u; } pk;
                    #pragma unroll
                    for (int cc = 0; cc < 4; ++cc)
                        pk.hh[cc] = __float2bfloat16(acc[q][cc] + b2[c0 + cc]);
                    *(uint2*)&((__hip_bfloat16*)Yv)[(size_t)row * NC2 + c0] = pk.u;
                } else {
                    #pragma unroll
                    for (int cc = 0; cc < CS2; ++cc)
                        ((float*)Yv)[(size_t)row * NC2 + c0 + cc] = acc[q][cc] + b2[c0 + cc];
                }
            }
        }
    }
}

// ---------------- fused update MLP + gated apply (+ fused decoder when LAST) ----------------
// LDS aliasing: svs reuses s2 (dead after phase-2 k-loop); sh reuses sX (dead after apply).
template<int LAST>
__global__ __launch_bounds__(312)
void k_updmlp_apply(const float* __restrict__ H, const float* __restrict__ vnorm,
                    const float* __restrict__ w1, const float* __restrict__ b1,
                    const float* __restrict__ w2, const float* __restrict__ b2,
                    const float* __restrict__ u_v, const float* __restrict__ dotb,
                    float* __restrict__ V, __hip_bfloat16* __restrict__ Vbf,
                    float* __restrict__ Hout,
                    const float* __restrict__ dw1, const float* __restrict__ db1,
                    const float* __restrict__ dw2, const float* __restrict__ db2,
                    float* __restrict__ dec_out)
{
    constexpr int R = 32;
    __shared__ float smem[156 * R + 78 * 33];
    float* sX = smem;              // 156*32
    float* s2 = smem + 156 * R;    // 78*33
    float* svs = s2;               // alias (LAST): relu(V.sum(-1))
    float* sh  = smem;             // alias (LAST): decoder hidden
    const int r0 = blockIdx.x * R;
    const int tid = threadIdx.y * 78 + threadIdx.x;
    for (int idx = tid; idx < R * 156; idx += 312) {
        int r = idx / 156, k = idx - r * 156;
        int row = r0 + r;
        sX[k * R + r] = (k < 78) ? H[(size_t)row * FF + k]
                                 : vnorm[(size_t)row * FF + (k - 78)];
    }
    __syncthreads();
    const int rg = threadIdx.y * 8;
    const int c = threadIdx.x;
    // phase 1: hid = silu([H|vnorm]@w1+b1)  (explicit b128 LDS reads)
    {
        float acc[8];
        #pragma unroll
        for (int q = 0; q < 8; ++q) acc[q] = 0.f;
        for (int k = 0; k < 156; ++k) {
            const float w = w1[k * 78 + c];
            const float4 xa = *(const float4*)&sX[k * R + rg];
            const float4 xb = *(const float4*)&sX[k * R + rg + 4];
            acc[0] = fmaf(w, xa.x, acc[0]); acc[1] = fmaf(w, xa.y, acc[1]);
            acc[2] = fmaf(w, xa.z, acc[2]); acc[3] = fmaf(w, xa.w, acc[3]);
            acc[4] = fmaf(w, xb.x, acc[4]); acc[5] = fmaf(w, xb.y, acc[5]);
            acc[6] = fmaf(w, xb.z, acc[6]); acc[7] = fmaf(w, xb.w, acc[7]);
        }
        const float bb = b1[c];
        #pragma unroll
        for (int q = 0; q < 8; ++q) {
            float y = acc[q] + bb;
            s2[c * 33 + rg + q] = y / (1.f + expf(-y));
        }
    }
    __syncthreads();
    // phase 2 + apply
    {
        float a0[8], a1[8], a2[8];
        #pragma unroll
        for (int q = 0; q < 8; ++q) { a0[q] = 0.f; a1[q] = 0.f; a2[q] = 0.f; }
        for (int k = 0; k < 78; ++k) {
            float xv[8];
            #pragma unroll
            for (int q = 0; q < 8; ++q) xv[q] = s2[k * 33 + rg + q];
            const float w0 = w2[k * F3 + c];
            const float w1v = w2[k * F3 + 78 + c];
            const float w2v = w2[k * F3 + 156 + c];
            #pragma unroll
            for (int q = 0; q < 8; ++q) {
                a0[q] = fmaf(xv[q], w0, a0[q]);
                a1[q] = fmaf(xv[q], w1v, a1[q]);
                a2[q] = fmaf(xv[q], w2v, a2[q]);
            }
        }
        if constexpr (LAST) __syncthreads();   // all s2 reads done before svs(=s2) writes
        const float bvv = b2[c], bsv = b2[78 + c], bss = b2[156 + c];
        #pragma unroll
        for (int q = 0; q < 8; ++q) {
            const int row = r0 + rg + q;
            const float avv = a0[q] + bvv, asv = a1[q] + bsv, ass = a2[q] + bss;
            const size_t b3 = (size_t)row * F3 + c * 3;
            const float u0 = u_v[b3], u1 = u_v[b3 + 1], u2 = u_v[b3 + 2];
            const float dot = dotb[(size_t)row * FF + c];
            Hout[(size_t)row * FF + c] = sX[c * R + rg + q] + asv * dot + ass;
            const float nv0 = V[b3]     + avv * u0;
            const float nv1 = V[b3 + 1] + avv * u1;
            const float nv2 = V[b3 + 2] + avv * u2;
            if constexpr (!LAST) {
                V[b3] = nv0; V[b3 + 1] = nv1; V[b3 + 2] = nv2;
                union { __hip_bfloat16 hh[4]; uint2 u; } pk;
                pk.hh[0] = __float2bfloat16(nv0);
                pk.hh[1] = __float2bfloat16(nv1);
                pk.hh[2] = __float2bfloat16(nv2);
                pk.hh[3] = __float2bfloat16(0.f);
                *(uint2*)&Vbf[(size_t)row * F4 + c * 4] = pk.u;
            } else {
                svs[c * 33 + rg + q] = fmaxf(nv0 + nv1 + nv2, 0.f);   // relu(V.sum(-1))
            }
        }
    }
    if constexpr (LAST) {
        __syncthreads();   // apply's sX reads done; svs complete
        // decoder layer 1: h = relu(vs@dw1+db1), 39 cols -> sh (aliases sX)
        for (int idx = tid; idx < 39 * 32; idx += 312) {
            const int r = idx / 39, o = idx - r * 39;
            float h = db1[o];
            for (int g = 0; g < 78; ++g) h = fmaf(svs[g * 33 + r], dw1[g * 39 + o], h);
            sh[o * 33 + r] = fmaxf(h, 0.f);
        }
        __syncthreads();
        // decoder layer 2: out = h@dw2+db2
        for (int idx = tid; idx < 39 * 32; idx += 312) {
            const int r = idx / 39, o = idx - r * 39;
            float oo = db2[o];
            for (int m = 0; m < 39; ++m) oo = fmaf(sh[m * 33 + r], dw2[m * 39 + o], oo);
            dec_out[(size_t)(r0 + r) * 39 + o] = oo;
        }
    }
}

// w-dot from rec row e (block-uniform addr) — packed fp32 FMA
#define COMP_W(E_, W_, UX_, UY_, UZ_) do {                                          \
    const float4* r4_ = (const float4*)(rec + (size_t)(E_) * REC_STRIDE);           \
    const float4 q0=r4_[0], q1=r4_[1], q2=r4_[2], q3=r4_[3], q4=r4_[4], q5=r4_[5];  \
    f2 A_ = mkf2(q0.x, q0.y) * wcol2[0];                                            \
    f2 B_ = mkf2(q0.z, q0.w) * wcol2[1];                                            \
    A_ = FMA2(mkf2(q1.x, q1.y), wcol2[2], A_);                                      \
    B_ = FMA2(mkf2(q1.z, q1.w), wcol2[3], B_);                                      \
    A_ = FMA2(mkf2(q2.x, q2.y), wcol2[4], A_);                                      \
    B_ = FMA2(mkf2(q2.z, q2.w), wcol2[5], B_);                                      \
    A_ = FMA2(mkf2(q3.x, q3.y), wcol2[6], A_);                                      \
    B_ = FMA2(mkf2(q3.z, q3.w), wcol2[7], B_);                                      \
    A_ = FMA2(mkf2(q4.x, q4.y), wcol2[8], A_);                                      \
    B_ = FMA2(mkf2(q4.z, q4.w), wcol2[9], B_);                                      \
    W_ = fmaf(wb, q5.x, (A_.x + B_.x) + (A_.y + B_.y));                             \
    UX_ = q5.y; UY_ = q5.z; UZ_ = q5.w;                                             \
} while (0)

// ---------------- layer-0 message: V==0 -> only s0 (H) and s2 (unit) survive ----------------
// 192 threads: [0,78)=s2*unit (phi ch 156+t), [78,156)=s0->H (phi ch t-78); rest idle clones.
// depth-3 phi gather pipeline.
__global__ __launch_bounds__(192)
void k_message_l0(const __hip_bfloat16* __restrict__ phi, const float* __restrict__ Hin,
                  float* __restrict__ Vnew, float* __restrict__ Hcur,
                  const float* __restrict__ rec, const int* __restrict__ jl,
                  const int* __restrict__ row_start,
                  const float* __restrict__ rbfw, const float* __restrict__ rbfb)
{
    const int i = blockIdx.x;
    const int t = threadIdx.x;
    const int tt = (t < 156) ? t : 78;                     // tail -> harmless s0 clones
    const int cch = (tt < 78) ? tt + 156 : tt - 78;        // phi/w channel
    const float sun = (tt < 78) ? 1.f : 0.f;

    __shared__ float s_acc[F3];
    __shared__ int s_j[CHUNK];

    const unsigned short* __restrict__ phiu = (const unsigned short*)phi;

    f2 wcol2[10];
    const float wb = rbfb[cch];
    #pragma unroll
    for (int k = 0; k < 10; ++k)
        wcol2[k] = mkf2(rbfw[(2 * k) * F4 + cch], rbfw[(2 * k + 1) * F4 + cch]);

    const int e0 = row_start[i], e1 = row_start[i + 1];
    float accH = 0.f, a0 = 0.f, a1 = 0.f, a2 = 0.f;

    for (int base = e0; base < e1; base += CHUNK) {
        const int len = (e1 - base < CHUNK) ? (e1 - base) : CHUNK;
        if (t < len) s_j[t] = jl[base + t];
        __syncthreads();

        // prologue: stages A,B,C = edges 0,1,2 (clamped)
        const int m1 = (1 < len) ? 1 : 0;
        const int m2q = (2 < len) ? 2 : 0;
        unsigned pfA = (unsigned)phiu[(size_t)s_j[0]  * F4 + cch];
        unsigned pfB = (unsigned)phiu[(size_t)s_j[m1] * F4 + cch];
        unsigned pfC = (unsigned)phiu[(size_t)s_j[m2q] * F4 + cch];
        float wA, uxA, uyA, uzA;
        COMP_W(base, wA, uxA, uyA, uzA);

        for (int m = 0; m < len; ++m) {
            const int mw = (m + 1 < len) ? m + 1 : 0;   // rec next
            const int m3 = (m + 3 < len) ? m + 3 : 0;   // gather 3 ahead
            float wN, uxN, uyN, uzN;
            COMP_W(base + mw, wN, uxN, uyN, uzN);
            const unsigned pfD = (unsigned)phiu[(size_t)s_j[m3] * F4 + cch];

            const float pv = __uint_as_float(pfA << 16) * wA;
            a0 = fmaf(pv, sun * uxA, a0);
            a1 = fmaf(pv, sun * uyA, a1);
            a2 = fmaf(pv, sun * uzA, a2);
            accH += pv;

            pfA = pfB; pfB = pfC; pfC = pfD;
            wA = wN; uxA = uxN; uyA = uyN; uzA = uzN;
        }
        __syncthreads();   // before next chunk overwrites s_j
    }

    if (t < 78) { s_acc[3*t] = a0; s_acc[3*t+1] = a1; s_acc[3*t+2] = a2; }
    __syncthreads();
    if (t >= 78 && t < 156) {
        const int c = t - 78;
        Hcur[(unsigned)(i * FF + c)] = Hin[(unsigned)(i * FF + c)] + accH;
    }
    for (int k = t; k < F3; k += 192)
        Vnew[(unsigned)(i * F3 + k)] = s_acc[k];
}

// ---------------- message pass (layers >=1): 1 node/block, depth-3 gather pipeline ----------------
// lane groups: [0,78)=g1 (s1*vj)  [78,156)=g3 (m3=Σinv*vj, cross deferred)
//              [156,234)=g0 (s0->H)  [234,312)=g2 (s2*unit)
__global__ __launch_bounds__(320)
void k_message(const __hip_bfloat16* __restrict__ phi, const float* __restrict__ Vold,
               const __hip_bfloat16* __restrict__ Vbf,
               float* __restrict__ Vnew, float* __restrict__ Hcur,
               const float* __restrict__ rec, const int* __restrict__ jl,
               const int* __restrict__ row_start,
               const float* __restrict__ rbfw, const float* __restrict__ rbfb)
{
    const int i = blockIdx.x;
    const int t = threadIdx.x;
    const int tt = (t < 312) ? t : 156;   // tail lanes -> harmless g0 clones
    const int cch = (tt < 78) ? tt + 78 : (tt < 156) ? tt + 156
                  : (tt < 234) ? tt - 156 : tt - 78;      // actual phi/w channel
    const int fv  = (tt < 78) ? tt : (tt < 156) ? tt - 78 : 0;
    const bool needvj = (tt < 156);
    const float sun = (tt >= 234) ? 1.f : 0.f;
    const float svj = (tt < 156) ? 1.f : 0.f;

    __shared__ float s_acc[3 * F3];
    __shared__ int s_j[CHUNK];

    const unsigned short* __restrict__ phiu = (const unsigned short*)phi;
    const unsigned short* __restrict__ vbfu = (const unsigned short*)Vbf;

    f2 wcol2[10];
    const float wb = rbfb[cch];
    #pragma unroll
    for (int k = 0; k < 10; ++k)
        wcol2[k] = mkf2(rbfw[(2 * k) * F4 + cch], rbfw[(2 * k + 1) * F4 + cch]);

    const int e0 = row_start[i], e1 = row_start[i + 1];
    float accH = 0.f, a0 = 0.f, a1 = 0.f, a2 = 0.f;

    float vix = 0.f, viy = 0.f, viz = 0.f;
    if (t >= 78 && t < 156) {   // g3 only
        const unsigned vb = (unsigned)i * F3 + (unsigned)fv * 3;
        vix = Vold[vb]; viy = Vold[vb + 1]; viz = Vold[vb + 2];
    }

    for (int base = e0; base < e1; base += CHUNK) {
        const int len = (e1 - base < CHUNK) ? (e1 - base) : CHUNK;
        if (t < len) s_j[t] = jl[base + t];
        __syncthreads();

        // prologue: stages A,B,C = edges 0,1,2 (clamped)
        const int m1 = (1 < len) ? 1 : 0;
        const int m2q = (2 < len) ? 2 : 0;
        const int jA0 = s_j[0], jB0 = s_j[m1], jC0 = s_j[m2q];
        unsigned pfA = (unsigned)phiu[(size_t)jA0 * F4 + cch];
        unsigned pfB = (unsigned)phiu[(size_t)jB0 * F4 + cch];
        unsigned pfC = (unsigned)phiu[(size_t)jC0 * F4 + cch];
        uint2 vqA = make_uint2(0u, 0u), vqB = make_uint2(0u, 0u), vqC = make_uint2(0u, 0u);
        if (needvj) {
            vqA = *(const uint2*)(vbfu + ((size_t)jA0 * F4 + 4u * fv));
            vqB = *(const uint2*)(vbfu + ((size_t)jB0 * F4 + 4u * fv));
            vqC = *(const uint2*)(vbfu + ((size_t)jC0 * F4 + 4u * fv));
        }
        float wA, uxA, uyA, uzA;
        COMP_W(base, wA, uxA, uyA, uzA);

        for (int m = 0; m < len; ++m) {
            const int mw = (m + 1 < len) ? m + 1 : 0;   // rec next
            const int m3 = (m + 3 < len) ? m + 3 : 0;   // gathers 3 ahead
            float wN, uxN, uyN, uzN;
            COMP_W(base + mw, wN, uxN, uyN, uzN);
            const int jD = s_j[m3];
            const unsigned pfD = (unsigned)phiu[(size_t)jD * F4 + cch];
            uint2 vqD = make_uint2(0u, 0u);
            if (needvj) vqD = *(const uint2*)(vbfu + ((size_t)jD * F4 + 4u * fv));

            // accumulate edge m from stage A
            const float pv  = __uint_as_float(pfA << 16) * wA;
            const float vj0 = __uint_as_float(vqA.x << 16);
            const float vj1 = __uint_as_float(vqA.x & 0xffff0000u);
            const float vj2 = __uint_as_float(vqA.y << 16);
            a0 = fmaf(pv, fmaf(svj, vj0, sun * uxA), a0);
            a1 = fmaf(pv, fmaf(svj, vj1, sun * uyA), a1);
            a2 = fmaf(pv, fmaf(svj, vj2, sun * uzA), a2);
            accH += pv;

            pfA = pfB; vqA = vqB;
            pfB = pfC; vqB = vqC;
            pfC = pfD; vqC = vqD;
            wA = wN; uxA = uxN; uyA = uyN; uzA = uzN;
        }
        __syncthreads();   // before next chunk overwrites s_j
    }

    // deferred cross for g3: contribution = vi x (sum inv3*vj)
    if (t >= 78 && t < 156) {
        const float m0 = a0, m1c = a1, m2c = a2;
        a0 = viy * m2c - viz * m1c;
        a1 = viz * m0  - vix * m2c;
        a2 = vix * m1c - viy * m0;
    }

    // merge the three vector groups via LDS (group-private regions)
    if (t < 78) {
        s_acc[3*tt] = a0; s_acc[3*tt+1] = a1; s_acc[3*tt+2] = a2;
    } else if (t < 156) {
        const int f = tt - 78;
        s_acc[F3 + 3*f] = a0; s_acc[F3 + 3*f+1] = a1; s_acc[F3 + 3*f+2] = a2;
    } else if (t >= 234 && t < 312) {
        const int f = tt - 234;
        s_acc[2*F3 + 3*f] = a0; s_acc[2*F3 + 3*f+1] = a1; s_acc[2*F3 + 3*f+2] = a2;
    }
    __syncthreads();
    if (t >= 156 && t < 234) Hcur[(unsigned)(i * FF + (t - 156))] += accH;
    for (int k = t; k < F3; k += 320)
        Vnew[(unsigned)(i * F3 + k)] = Vold[(unsigned)(i * F3 + k)]
            + s_acc[k] + s_acc[F3 + k] + s_acc[2*F3 + k];
}

// ---------------- u_v einsum + dot(u,v) + v_norm, 16 nodes/block, time-multiplexed sV ----------------
__global__ __launch_bounds__(256)
void k_upd_uv(const float* __restrict__ V, const float* __restrict__ wu, const float* __restrict__ wv,
              float* __restrict__ u_v, float* __restrict__ dotb, float* __restrict__ vnorm)
{
    const int n0 = blockIdx.x * UV_RN;
    const int t = threadIdx.x;
    __shared__ float sV[UV_RN][240];   // [n][k] padded (234 -> 240); reused 3 phases
    for (int idx = t; idx < F3 * UV_RN; idx += 256) {
        int n = idx / F3, k = idx - n * F3;
        sV[n][k] = V[(size_t)(n0 + n) * F3 + k];
    }
    __syncthreads();
    float au[UV_RN], av[UV_RN];
    #pragma unroll
    for (int n = 0; n < UV_RN; ++n) { au[n] = 0.f; av[n] = 0.f; }
    if (t < F3) {
        const int g = t / 3, c = t - g * 3;
        for (int f = 0; f < FF; ++f) {
            const float wuv = wu[f * FF + g];
            const float wvv = wv[f * FF + g];
            const int kk = f * 3 + c;
            #pragma unroll
            for (int n = 0; n < UV_RN; ++n) {
                const float x = sV[n][kk];        // 3 distinct addrs -> broadcast
                au[n] = fmaf(x, wuv, au[n]);
                av[n] = fmaf(x, wvv, av[n]);
            }
        }
        #pragma unroll
        for (int n = 0; n < UV_RN; ++n)
            u_v[(size_t)(n0 + n) * F3 + t] = au[n];
    }
    __syncthreads();
    if (t < F3) {
        #pragma unroll
        for (int n = 0; n < UV_RN; ++n) sV[n][t] = av[n];   // phase 2: v values
    }
    __syncthreads();
    for (int idx = t; idx < FF * UV_RN; idx += 256) {
        int n = idx / FF, g = idx - n * FF;   // g fast -> coalesced vnorm write
        float a = sV[n][3*g], b = sV[n][3*g+1], c = sV[n][3*g+2];
        vnorm[(size_t)(n0 + n) * FF + g] = sqrtf(a * a + b * b + c * c + EPS_F);
    }
    __syncthreads();
    if (t < F3) {
        #pragma unroll
        for (int n = 0; n < UV_RN; ++n) sV[n][t] = au[n] * av[n];   // phase 3: u*v
    }
    __syncthreads();
    for (int idx = t; idx < FF * UV_RN; idx += 256) {
        int n = idx / FF, g = idx - n * FF;
        dotb[(size_t)(n0 + n) * FF + g] = sV[n][3*g] + sV[n][3*g+1] + sV[n][3*g+2];
    }
}

extern "C" void kernel_launch(void* const* d_in, const int* in_sizes, int n_in,
                              void* d_out, int out_size, void* d_ws, size_t ws_size,
                              hipStream_t stream)
{
    const float* xyz    = (const float*)d_in[0];
    const int*   nbr    = (const int*)  d_in[1];
    const float* Hin    = (const float*)d_in[3];
    const float* msg_w1 = (const float*)d_in[4];
    const float* msg_b1 = (const float*)d_in[5];
    const float* msg_w2 = (const float*)d_in[6];
    const float* msg_b2 = (const float*)d_in[7];
    const float* rbf_w  = (const float*)d_in[8];
    const float* rbf_b  = (const float*)d_in[9];
    const float* upd_wu = (const float*)d_in[10];
    const float* upd_wv = (const float*)d_in[11];
    const float* upd_w1 = (const float*)d_in[12];
    const float* upd_b1 = (const float*)d_in[13];
    const float* upd_w2 = (const float*)d_in[14];
    const float* upd_b2 = (const float*)d_in[15];
    const float* dw1    = (const float*)d_in[16];
    const float* db1    = (const float*)d_in[17];
    const float* dw2    = (const float*)d_in[18];
    const float* db2    = (const float*)d_in[19];
    const int E = in_sizes[1] / 2;
    const int ECAP = E / 2 + E / 25;   // active edges deterministic ~47%; cap 54%

    float* ws = (float*)d_ws;
    size_t off = 0;
    float* Hcur  = ws + off; off += (size_t)N_NODES * FF;
    float* VA    = ws + off; off += (size_t)N_NODES * F3;
    float* VB    = ws + off; off += (size_t)N_NODES * F3;
    __hip_bfloat16* phi = (__hip_bfloat16*)(ws + off); off += (size_t)N_NODES * F4 / 2;  // bf16
    __hip_bfloat16* Vbf = (__hip_bfloat16*)(ws + off); off += (size_t)N_NODES * F4 / 2;  // bf16x4 rows
    float* u_v   = ws + off; off += (size_t)N_NODES * F3;
    float* dotb  = ws + off; off += (size_t)N_NODES * FF;
    float* vnorm = ws + off; off += (size_t)N_NODES * FF;
    float* rec   = ws + off; off += (size_t)ECAP * REC_STRIDE;
    int* ibase     = (int*)(ws + off);
    int* row_start = ibase;                       // N+1
    int* counts    = row_start + (N_NODES + 1);   // N
    int* cursor    = counts + N_NODES;            // N
    int* jl        = cursor + N_NODES;            // ECAP

    k_init<<<dim3((N_NODES + 255) / 256), dim3(256), 0, stream>>>(counts, cursor);
    k_geo<<<dim3((E + 255) / 256), dim3(256), 0, stream>>>(xyz, nbr, counts, E);
    k_scan<<<dim3(1), dim3(1024), 0, stream>>>(counts, row_start, N_NODES);
    k_fill<<<dim3((E + 255) / 256), dim3(256), 0, stream>>>(xyz, nbr, row_start, cursor, rec, jl, E);

    float* dout = (float*)d_out;
    float* Vold = VA;
    float* Vnew = VB;
    for (int l = 0; l < NL; ++l) {
        // phi = silu(H@w1+b1)@w2+b2  (fused, bf16 out); layer 0 reads Hin directly
        const float* Hsrc = (l == 0) ? Hin : Hcur;
        k_mlp2<78, 0, 312, 4, 1><<<dim3(625), dim3(78, 4), 0, stream>>>(
            Hsrc, nullptr, msg_w1 + (size_t)l * 78 * 78, msg_b1 + (size_t)l * 78,
            msg_w2 + (size_t)l * 78 * 312, msg_b2 + (size_t)l * 312, phi, N_NODES);
        // message pass
        if (l == 0)
            k_message_l0<<<dim3(N_NODES), dim3(192), 0, stream>>>(
                phi, Hin, Vnew, Hcur, rec, jl, row_start,
                rbf_w + (size_t)l * NRBF * F4, rbf_b + (size_t)l * F4);
        else
            k_message<<<dim3(N_NODES), dim3(320), 0, stream>>>(
                phi, Vold, Vbf, Vnew, Hcur, rec, jl, row_start,
                rbf_w + (size_t)l * NRBF * F4, rbf_b + (size_t)l * F4);
        // u_v, dot(u,v), v_norm
        k_upd_uv<<<dim3(N_NODES / UV_RN), dim3(256), 0, stream>>>(
            Vnew, upd_wu + (size_t)l * 78 * 78, upd_wv + (size_t)l * 78 * 78, u_v, dotb, vnorm);
        // fused: a = silu([H|vnorm]@uw1+ub1)@uw2+ub2 ; apply to H,V ; (+decoder when last)
        if (l == NL - 1)
            k_updmlp_apply<1><<<dim3(625), dim3(78, 4), 0, stream>>>(
                Hcur, vnorm, upd_w1 + (size_t)l * 156 * 78, upd_b1 + (size_t)l * 78,
                upd_w2 + (size_t)l * 78 * 234, upd_b2 + (size_t)l * 234,
                u_v, dotb, Vnew, Vbf, dout,
                dw1, db1, dw2, db2, dout + (size_t)N_NODES * FF);
        else
            k_updmlp_apply<0><<<dim3(625), dim3(78, 4), 0, stream>>>(
                Hcur, vnorm, upd_w1 + (size_t)l * 156 * 78, upd_b1 + (size_t)l * 78,
                upd_w2 + (size_t)l * 78 * 234, upd_b2 + (size_t)l * 234,
                u_v, dotb, Vnew, Vbf, Hcur,
                dw1, db1, dw2, db2, nullptr);
        float* tmp = Vold; Vold = Vnew; Vnew = tmp;
    }
}

// Round 19
// 675.337 us; speedup vs baseline: 1.0369x; 1.0369x over previous
//
#include <hip/hip_runtime.h>
#include <hip/hip_bf16.h>
#include <cmath>

#define N_NODES 20000
#define FF 78
#define F3 234   // 3*78
#define F4 312   // 4*78
#define NRBF 20
#define CUTOFF 21.0f
#define NL 3
#define PI_F 3.14159265358979323846f
#define EPS_F 1e-15f
#define REC_STRIDE 24
#define CHUNK 64
#define UV_RN 16  // nodes per block in k_upd_uv

typedef float f2 __attribute__((ext_vector_type(2)));
static __device__ __forceinline__ f2 mkf2(float a, float b) { f2 r; r.x = a; r.y = b; return r; }
#if defined(__has_builtin)
# if __has_builtin(__builtin_elementwise_fma)
#  define FMA2(a,b,c) __builtin_elementwise_fma((a),(b),(c))
# endif
#endif
#ifndef FMA2
static __device__ __forceinline__ f2 fma2_(f2 a, f2 b, f2 c) {
    f2 r; r.x = fmaf(a.x, b.x, c.x); r.y = fmaf(a.y, b.y, c.y); return r;
}
# define FMA2(a,b,c) fma2_((a),(b),(c))
#endif

// ---------------- init: zero counts/cursor only (H handled by l0 kernels) ----------------
__global__ void k_init(int* __restrict__ counts, int* __restrict__ cursor)
{
    int idx = blockIdx.x * blockDim.x + threadIdx.x;
    if (idx < N_NODES) { counts[idx] = 0; cursor[idx] = 0; }
}

// ---------------- active-edge degree count (geometry recomputed in k_fill) ----------------
__global__ void k_geo(const float* __restrict__ xyz, const int* __restrict__ nbr,
                      int* __restrict__ counts, int E)
{
    int e = blockIdx.x * blockDim.x + threadIdx.x;
    if (e >= E) return;
    int i = nbr[2 * e], j = nbr[2 * e + 1];
    float rx = xyz[3 * j]     - xyz[3 * i];
    float ry = xyz[3 * j + 1] - xyz[3 * i + 1];
    float rz = xyz[3 * j + 2] - xyz[3 * i + 2];
    float d = sqrtf(rx * rx + ry * ry + rz * rz + 3.0f * EPS_F);
    if (d < CUTOFF) atomicAdd(&counts[i], 1);   // env==0 edges contribute exactly nothing
}

// ---------------- exclusive scan of counts -> row_start (single block, 1024 thr) ----------------
__global__ __launch_bounds__(1024)
void k_scan(const int* __restrict__ counts, int* __restrict__ row_start, int n)
{
    __shared__ int s[1024];
    const int t = threadIdx.x;
    constexpr int PER = 20;                 // 1024*20 = 20480 >= n+1
    const int base = t * PER;
    int loc[PER];
    int sum = 0;
    #pragma unroll
    for (int q = 0; q < PER; ++q) {
        int idx = base + q;
        int v = (idx < n) ? counts[idx] : 0;
        loc[q] = sum;
        sum += v;
    }
    s[t] = sum;
    __syncthreads();
    for (int off = 1; off < 1024; off <<= 1) {
        int add = (t >= off) ? s[t - off] : 0;
        __syncthreads();
        s[t] += add;
        __syncthreads();
    }
    const int excl = (t > 0) ? s[t - 1] : 0;
    #pragma unroll
    for (int q = 0; q < PER; ++q) {
        int idx = base + q;
        if (idx <= n) row_start[idx] = excl + loc[q];
    }
}

// ---------------- fill CSR + edge record in one pass (Chebyshev sin recurrence) ----------------
__global__ void k_fill(const float* __restrict__ xyz, const int* __restrict__ nbr,
                       const int* __restrict__ row_start, int* __restrict__ cursor,
                       float* __restrict__ rec, int* __restrict__ jl, int E)
{
    int e = blockIdx.x * blockDim.x + threadIdx.x;
    if (e >= E) return;
    int i = nbr[2 * e], j = nbr[2 * e + 1];
    float rx = xyz[3 * j]     - xyz[3 * i];
    float ry = xyz[3 * j + 1] - xyz[3 * i + 1];
    float rz = xyz[3 * j + 2] - xyz[3 * i + 2];
    float d = sqrtf(rx * rx + ry * ry + rz * rz + 3.0f * EPS_F);
    if (d < CUTOFF) {
        int pos = row_start[i] + atomicAdd(&cursor[i], 1);
        float theta = PI_F * d / CUTOFF;
        float s1, c1;
        sincosf(theta, &s1, &c1);
        float env = 0.5f * (c1 + 1.0f);
        float envd = env / d;
        float inv_d = 1.f / d;
        float* r = rec + (size_t)pos * REC_STRIDE;
        float twoc = 2.f * c1;
        float skm = 0.f, sk = s1;
        r[0] = envd * sk;
        #pragma unroll
        for (int k = 1; k < NRBF; ++k) {
            float sk1 = twoc * sk - skm;
            r[k] = envd * sk1;
            skm = sk; sk = sk1;
        }
        r[20] = env;
        r[21] = rx * inv_d; r[22] = ry * inv_d; r[23] = rz * inv_d;
        jl[pos] = j;
    }
}

// ---------------- fused 2-layer MLP (message): phi = silu(H@w1+b1)@w2+b2 -> bf16 ----------------
template<int K1T, int K2T, int NC2, int CS2, int BF16OUT>
__global__ void k_mlp2(const float* __restrict__ X1, const float* __restrict__ X2,
                       const float* __restrict__ w1, const float* __restrict__ b1,
                       const float* __restrict__ w2, const float* __restrict__ b2,
                       void* __restrict__ Yv, int nrows)
{
    constexpr int R = 32;
    constexpr int K = K1T + K2T;
    __shared__ float sX[K * R];
    __shared__ float s2[78 * 33];
    const int r0 = blockIdx.x * R;
    const int tid = threadIdx.y * 78 + threadIdx.x;
    for (int idx = tid; idx < R * K; idx += 312) {
        int r = idx / K, k = idx - r * K;
        int row = r0 + r;
        float v = 0.f;
        if (row < nrows) {
            if constexpr (K2T == 0) v = X1[(size_t)row * K1T + k];
            else v = (k < K1T) ? X1[(size_t)row * K1T + k] : X2[(size_t)row * K2T + (k - K1T)];
        }
        sX[k * R + r] = v;
    }
    __syncthreads();
    const int rg = threadIdx.y * 8;
    // phase 1: hid = silu(X@w1+b1)
    {
        const int c = threadIdx.x;
        float acc[8];
        #pragma unroll
        for (int q = 0; q < 8; ++q) acc[q] = 0.f;
        for (int k = 0; k < K; ++k) {
            const float w = w1[k * 78 + c];
            #pragma unroll
            for (int q = 0; q < 8; ++q) acc[q] = fmaf(w, sX[k * R + rg + q], acc[q]);
        }
        const float bb = b1[c];
        #pragma unroll
        for (int q = 0; q < 8; ++q) {
            float y = acc[q] + bb;
            y = y / (1.f + expf(-y));
            s2[c * 33 + rg + q] = y;
        }
    }
    __syncthreads();
    // phase 2: Y = hid@w2+b2
    {
        const int c0 = threadIdx.x * CS2;
        float acc[8][CS2];
        #pragma unroll
        for (int q = 0; q < 8; ++q)
            #pragma unroll
            for (int cc = 0; cc < CS2; ++cc) acc[q][cc] = 0.f;
        for (int k = 0; k < 78; ++k) {
            float xv[8];
            #pragma unroll
            for (int q = 0; q < 8; ++q) xv[q] = s2[k * 33 + rg + q];
            float wv[CS2];
            #pragma unroll
            for (int cc = 0; cc < CS2; ++cc) wv[cc] = w2[(size_t)k * NC2 + c0 + cc];
            #pragma unroll
            for (int q = 0; q < 8; ++q)
                #pragma unroll
                for (int cc = 0; cc < CS2; ++cc) acc[q][cc] = fmaf(xv[q], wv[cc], acc[q][cc]);
        }
        #pragma unroll
        for (int q = 0; q < 8; ++q) {
            int row = r0 + rg + q;
            if (row < nrows) {
                if constexpr (BF16OUT && CS2 == 4) {
                    union { __hip_bfloat16 hh[4]; uint2 u; } pk;
                    #pragma unroll
                    for (int cc = 0; cc < 4; ++cc)
                        pk.hh[cc] = __float2bfloat16(acc[q][cc] + b2[c0 + cc]);
                    *(uint2*)&((__hip_bfloat16*)Yv)[(size_t)row * NC2 + c0] = pk.u;
                } else {
                    #pragma unroll
                    for (int cc = 0; cc < CS2; ++cc)
                        ((float*)Yv)[(size_t)row * NC2 + c0 + cc] = acc[q][cc] + b2[c0 + cc];
                }
            }
        }
    }
}

// ---------------- fused update MLP + gated apply (+ fused decoder when LAST) ----------------
// LDS aliasing: svs reuses s2 (dead after phase-2 k-loop); sh reuses sX (dead after apply).
template<int LAST>
__global__ __launch_bounds__(312)
void k_updmlp_apply(const float* __restrict__ H, const float* __restrict__ vnorm,
                    const float* __restrict__ w1, const float* __restrict__ b1,
                    const float* __restrict__ w2, const float* __restrict__ b2,
                    const float* __restrict__ u_v, const float* __restrict__ dotb,
                    float* __restrict__ V, __hip_bfloat16* __restrict__ Vbf,
                    float* __restrict__ Hout,
                    const float* __restrict__ dw1, const float* __restrict__ db1,
                    const float* __restrict__ dw2, const float* __restrict__ db2,
                    float* __restrict__ dec_out)
{
    constexpr int R = 32;
    __shared__ float smem[156 * R + 78 * 33];
    float* sX = smem;              // 156*32
    float* s2 = smem + 156 * R;    // 78*33
    float* svs = s2;               // alias (LAST): relu(V.sum(-1))
    float* sh  = smem;             // alias (LAST): decoder hidden
    const int r0 = blockIdx.x * R;
    const int tid = threadIdx.y * 78 + threadIdx.x;
    for (int idx = tid; idx < R * 156; idx += 312) {
        int r = idx / 156, k = idx - r * 156;
        int row = r0 + r;
        sX[k * R + r] = (k < 78) ? H[(size_t)row * FF + k]
                                 : vnorm[(size_t)row * FF + (k - 78)];
    }
    __syncthreads();
    const int rg = threadIdx.y * 8;
    const int c = threadIdx.x;
    // phase 1: hid = silu([H|vnorm]@w1+b1)
    {
        float acc[8];
        #pragma unroll
        for (int q = 0; q < 8; ++q) acc[q] = 0.f;
        for (int k = 0; k < 156; ++k) {
            const float w = w1[k * 78 + c];
            #pragma unroll
            for (int q = 0; q < 8; ++q) acc[q] = fmaf(w, sX[k * R + rg + q], acc[q]);
        }
        const float bb = b1[c];
        #pragma unroll
        for (int q = 0; q < 8; ++q) {
            float y = acc[q] + bb;
            s2[c * 33 + rg + q] = y / (1.f + expf(-y));
        }
    }
    __syncthreads();
    // phase 2 + apply
    {
        float a0[8], a1[8], a2[8];
        #pragma unroll
        for (int q = 0; q < 8; ++q) { a0[q] = 0.f; a1[q] = 0.f; a2[q] = 0.f; }
        for (int k = 0; k < 78; ++k) {
            float xv[8];
            #pragma unroll
            for (int q = 0; q < 8; ++q) xv[q] = s2[k * 33 + rg + q];
            const float w0 = w2[k * F3 + c];
            const float w1v = w2[k * F3 + 78 + c];
            const float w2v = w2[k * F3 + 156 + c];
            #pragma unroll
            for (int q = 0; q < 8; ++q) {
                a0[q] = fmaf(xv[q], w0, a0[q]);
                a1[q] = fmaf(xv[q], w1v, a1[q]);
                a2[q] = fmaf(xv[q], w2v, a2[q]);
            }
        }
        if constexpr (LAST) __syncthreads();   // all s2 reads done before svs(=s2) writes
        const float bvv = b2[c], bsv = b2[78 + c], bss = b2[156 + c];
        #pragma unroll
        for (int q = 0; q < 8; ++q) {
            const int row = r0 + rg + q;
            const float avv = a0[q] + bvv, asv = a1[q] + bsv, ass = a2[q] + bss;
            const size_t b3 = (size_t)row * F3 + c * 3;
            const float u0 = u_v[b3], u1 = u_v[b3 + 1], u2 = u_v[b3 + 2];
            const float dot = dotb[(size_t)row * FF + c];
            Hout[(size_t)row * FF + c] = sX[c * R + rg + q] + asv * dot + ass;
            const float nv0 = V[b3]     + avv * u0;
            const float nv1 = V[b3 + 1] + avv * u1;
            const float nv2 = V[b3 + 2] + avv * u2;
            if constexpr (!LAST) {
                V[b3] = nv0; V[b3 + 1] = nv1; V[b3 + 2] = nv2;
                union { __hip_bfloat16 hh[4]; uint2 u; } pk;
                pk.hh[0] = __float2bfloat16(nv0);
                pk.hh[1] = __float2bfloat16(nv1);
                pk.hh[2] = __float2bfloat16(nv2);
                pk.hh[3] = __float2bfloat16(0.f);
                *(uint2*)&Vbf[(size_t)row * F4 + c * 4] = pk.u;
            } else {
                svs[c * 33 + rg + q] = fmaxf(nv0 + nv1 + nv2, 0.f);   // relu(V.sum(-1))
            }
        }
    }
    if constexpr (LAST) {
        __syncthreads();   // apply's sX reads done; svs complete
        // decoder layer 1: h = relu(vs@dw1+db1), 39 cols -> sh (aliases sX)
        for (int idx = tid; idx < 39 * 32; idx += 312) {
            const int r = idx / 39, o = idx - r * 39;
            float h = db1[o];
            for (int g = 0; g < 78; ++g) h = fmaf(svs[g * 33 + r], dw1[g * 39 + o], h);
            sh[o * 33 + r] = fmaxf(h, 0.f);
        }
        __syncthreads();
        // decoder layer 2: out = h@dw2+db2
        for (int idx = tid; idx < 39 * 32; idx += 312) {
            const int r = idx / 39, o = idx - r * 39;
            float oo = db2[o];
            for (int m = 0; m < 39; ++m) oo = fmaf(sh[m * 33 + r], dw2[m * 39 + o], oo);
            dec_out[(size_t)(r0 + r) * 39 + o] = oo;
        }
    }
}

// w-dot from rec row e (block-uniform addr) — packed fp32 FMA
#define COMP_W(E_, W_, UX_, UY_, UZ_) do {                                          \
    const float4* r4_ = (const float4*)(rec + (size_t)(E_) * REC_STRIDE);           \
    const float4 q0=r4_[0], q1=r4_[1], q2=r4_[2], q3=r4_[3], q4=r4_[4], q5=r4_[5];  \
    f2 A_ = mkf2(q0.x, q0.y) * wcol2[0];                                            \
    f2 B_ = mkf2(q0.z, q0.w) * wcol2[1];                                            \
    A_ = FMA2(mkf2(q1.x, q1.y), wcol2[2], A_);                                      \
    B_ = FMA2(mkf2(q1.z, q1.w), wcol2[3], B_);                                      \
    A_ = FMA2(mkf2(q2.x, q2.y), wcol2[4], A_);                                      \
    B_ = FMA2(mkf2(q2.z, q2.w), wcol2[5], B_);                                      \
    A_ = FMA2(mkf2(q3.x, q3.y), wcol2[6], A_);                                      \
    B_ = FMA2(mkf2(q3.z, q3.w), wcol2[7], B_);                                      \
    A_ = FMA2(mkf2(q4.x, q4.y), wcol2[8], A_);                                      \
    B_ = FMA2(mkf2(q4.z, q4.w), wcol2[9], B_);                                      \
    W_ = fmaf(wb, q5.x, (A_.x + B_.x) + (A_.y + B_.y));                             \
    UX_ = q5.y; UY_ = q5.z; UZ_ = q5.w;                                             \
} while (0)

// ---------------- layer-0 message: V==0 -> only s0 (H) and s2 (unit) survive ----------------
// 192 threads: [0,78)=s2*unit (phi ch 156+t), [78,156)=s0->H (phi ch t-78); rest idle clones.
__global__ __launch_bounds__(192)
void k_message_l0(const __hip_bfloat16* __restrict__ phi, const float* __restrict__ Hin,
                  float* __restrict__ Vnew, float* __restrict__ Hcur,
                  const float* __restrict__ rec, const int* __restrict__ jl,
                  const int* __restrict__ row_start,
                  const float* __restrict__ rbfw, const float* __restrict__ rbfb)
{
    const int i = blockIdx.x;
    const int t = threadIdx.x;
    const int tt = (t < 156) ? t : 78;                     // tail -> harmless s0 clones
    const int cch = (tt < 78) ? tt + 156 : tt - 78;        // phi/w channel
    const float sun = (tt < 78) ? 1.f : 0.f;

    __shared__ float s_acc[F3];
    __shared__ int s_j[CHUNK];

    const unsigned short* __restrict__ phiu = (const unsigned short*)phi;

    f2 wcol2[10];
    const float wb = rbfb[cch];
    #pragma unroll
    for (int k = 0; k < 10; ++k)
        wcol2[k] = mkf2(rbfw[(2 * k) * F4 + cch], rbfw[(2 * k + 1) * F4 + cch]);

    const int e0 = row_start[i], e1 = row_start[i + 1];
    float accH = 0.f, a0 = 0.f, a1 = 0.f, a2 = 0.f;

    for (int base = e0; base < e1; base += CHUNK) {
        const int len = (e1 - base < CHUNK) ? (e1 - base) : CHUNK;
        if (t < len) s_j[t] = jl[base + t];
        __syncthreads();

        // prologue: stage A = edge 0, stage B = edge 1 (clamped)
        int jA = s_j[0];
        unsigned pfA = (unsigned)phiu[(size_t)jA * F4 + cch];
        const int m1 = (1 < len) ? 1 : 0;
        int jB = s_j[m1];
        unsigned pfB = (unsigned)phiu[(size_t)jB * F4 + cch];
        float wA, uxA, uyA, uzA;
        COMP_W(base, wA, uxA, uyA, uzA);

        for (int m = 0; m < len; ++m) {
            const int mw = (m + 1 < len) ? m + 1 : 0;   // rec next
            const int m2 = (m + 2 < len) ? m + 2 : 0;   // gather 2 ahead
            float wN, uxN, uyN, uzN;
            COMP_W(base + mw, wN, uxN, uyN, uzN);
            const int jC = s_j[m2];
            const unsigned pfC = (unsigned)phiu[(size_t)jC * F4 + cch];

            const float pv = __uint_as_float(pfA << 16) * wA;
            a0 = fmaf(pv, sun * uxA, a0);
            a1 = fmaf(pv, sun * uyA, a1);
            a2 = fmaf(pv, sun * uzA, a2);
            accH += pv;

            pfA = pfB;
            wA = wN; uxA = uxN; uyA = uyN; uzA = uzN;
            pfB = pfC;
        }
        __syncthreads();   // before next chunk overwrites s_j
    }

    if (t < 78) { s_acc[3*t] = a0; s_acc[3*t+1] = a1; s_acc[3*t+2] = a2; }
    __syncthreads();
    if (t >= 78 && t < 156) {
        const int c = t - 78;
        Hcur[(unsigned)(i * FF + c)] = Hin[(unsigned)(i * FF + c)] + accH;
    }
    for (int k = t; k < F3; k += 192)
        Vnew[(unsigned)(i * F3 + k)] = s_acc[k];
}

// ---------------- message pass (layers >=1): 1 node/block, remapped groups ----------------
// lane groups: [0,78)=g1 (s1*vj)  [78,156)=g3 (m3=Σinv*vj, cross deferred)
//              [156,234)=g0 (s0->H)  [234,312)=g2 (s2*unit)
__global__ __launch_bounds__(320)
void k_message(const __hip_bfloat16* __restrict__ phi, const float* __restrict__ Vold,
               const __hip_bfloat16* __restrict__ Vbf,
               float* __restrict__ Vnew, float* __restrict__ Hcur,
               const float* __restrict__ rec, const int* __restrict__ jl,
               const int* __restrict__ row_start,
               const float* __restrict__ rbfw, const float* __restrict__ rbfb)
{
    const int i = blockIdx.x;
    const int t = threadIdx.x;
    const int tt = (t < 312) ? t : 156;   // tail lanes -> harmless g0 clones
    const int cch = (tt < 78) ? tt + 78 : (tt < 156) ? tt + 156
                  : (tt < 234) ? tt - 156 : tt - 78;      // actual phi/w channel
    const int fv  = (tt < 78) ? tt : (tt < 156) ? tt - 78 : 0;
    const bool needvj = (tt < 156);
    const float sun = (tt >= 234) ? 1.f : 0.f;
    const float svj = (tt < 156) ? 1.f : 0.f;

    __shared__ float s_acc[3 * F3];
    __shared__ int s_j[CHUNK];

    const unsigned short* __restrict__ phiu = (const unsigned short*)phi;
    const unsigned short* __restrict__ vbfu = (const unsigned short*)Vbf;

    f2 wcol2[10];
    const float wb = rbfb[cch];
    #pragma unroll
    for (int k = 0; k < 10; ++k)
        wcol2[k] = mkf2(rbfw[(2 * k) * F4 + cch], rbfw[(2 * k + 1) * F4 + cch]);

    const int e0 = row_start[i], e1 = row_start[i + 1];
    float accH = 0.f, a0 = 0.f, a1 = 0.f, a2 = 0.f;

    float vix = 0.f, viy = 0.f, viz = 0.f;
    if (t >= 78 && t < 156) {   // g3 only
        const unsigned vb = (unsigned)i * F3 + (unsigned)fv * 3;
        vix = Vold[vb]; viy = Vold[vb + 1]; viz = Vold[vb + 2];
    }

    for (int base = e0; base < e1; base += CHUNK) {
        const int len = (e1 - base < CHUNK) ? (e1 - base) : CHUNK;
        if (t < len) s_j[t] = jl[base + t];
        __syncthreads();

        // prologue: stage A = edge 0, stage B = edge 1 (clamped)
        int jA = s_j[0];
        unsigned pfA = (unsigned)phiu[(size_t)jA * F4 + cch];
        uint2 vqA = make_uint2(0u, 0u);
        if (needvj) vqA = *(const uint2*)(vbfu + ((size_t)jA * F4 + 4u * fv));
        const int m1 = (1 < len) ? 1 : 0;
        int jB = s_j[m1];
        unsigned pfB = (unsigned)phiu[(size_t)jB * F4 + cch];
        uint2 vqB = make_uint2(0u, 0u);
        if (needvj) vqB = *(const uint2*)(vbfu + ((size_t)jB * F4 + 4u * fv));
        float wA, uxA, uyA, uzA;
        COMP_W(base, wA, uxA, uyA, uzA);

        for (int m = 0; m < len; ++m) {
            const int mw = (m + 1 < len) ? m + 1 : 0;   // rec next
            const int m2 = (m + 2 < len) ? m + 2 : 0;   // gathers 2 ahead
            float wN, uxN, uyN, uzN;
            COMP_W(base + mw, wN, uxN, uyN, uzN);
            const int jC = s_j[m2];
            const unsigned pfC = (unsigned)phiu[(size_t)jC * F4 + cch];
            uint2 vqC = make_uint2(0u, 0u);
            if (needvj) vqC = *(const uint2*)(vbfu + ((size_t)jC * F4 + 4u * fv));

            // accumulate edge m from stage A
            const float pv  = __uint_as_float(pfA << 16) * wA;
            const float vj0 = __uint_as_float(vqA.x << 16);
            const float vj1 = __uint_as_float(vqA.x & 0xffff0000u);
            const float vj2 = __uint_as_float(vqA.y << 16);
            a0 = fmaf(pv, fmaf(svj, vj0, sun * uxA), a0);
            a1 = fmaf(pv, fmaf(svj, vj1, sun * uyA), a1);
            a2 = fmaf(pv, fmaf(svj, vj2, sun * uzA), a2);
            accH += pv;

            pfA = pfB; vqA = vqB;
            wA = wN; uxA = uxN; uyA = uyN; uzA = uzN;
            pfB = pfC; vqB = vqC;
        }
        __syncthreads();   // before next chunk overwrites s_j
    }

    // deferred cross for g3: contribution = vi x (sum inv3*vj)
    if (t >= 78 && t < 156) {
        const float m0 = a0, m1c = a1, m2c = a2;
        a0 = viy * m2c - viz * m1c;
        a1 = viz * m0  - vix * m2c;
        a2 = vix * m1c - viy * m0;
    }

    // merge the three vector groups via LDS (group-private regions)
    if (t < 78) {
        s_acc[3*tt] = a0; s_acc[3*tt+1] = a1; s_acc[3*tt+2] = a2;
    } else if (t < 156) {
        const int f = tt - 78;
        s_acc[F3 + 3*f] = a0; s_acc[F3 + 3*f+1] = a1; s_acc[F3 + 3*f+2] = a2;
    } else if (t >= 234 && t < 312) {
        const int f = tt - 234;
        s_acc[2*F3 + 3*f] = a0; s_acc[2*F3 + 3*f+1] = a1; s_acc[2*F3 + 3*f+2] = a2;
    }
    __syncthreads();
    if (t >= 156 && t < 234) Hcur[(unsigned)(i * FF + (t - 156))] += accH;
    for (int k = t; k < F3; k += 320)
        Vnew[(unsigned)(i * F3 + k)] = Vold[(unsigned)(i * F3 + k)]
            + s_acc[k] + s_acc[F3 + k] + s_acc[2*F3 + k];
}

// ---------------- u_v einsum + dot(u,v) + v_norm, 16 nodes/block, time-multiplexed sV ----------------
__global__ __launch_bounds__(256)
void k_upd_uv(const float* __restrict__ V, const float* __restrict__ wu, const float* __restrict__ wv,
              float* __restrict__ u_v, float* __restrict__ dotb, float* __restrict__ vnorm)
{
    const int n0 = blockIdx.x * UV_RN;
    const int t = threadIdx.x;
    __shared__ float sV[UV_RN][240];   // [n][k] padded (234 -> 240); reused 3 phases
    for (int idx = t; idx < F3 * UV_RN; idx += 256) {
        int n = idx / F3, k = idx - n * F3;
        sV[n][k] = V[(size_t)(n0 + n) * F3 + k];
    }
    __syncthreads();
    float au[UV_RN], av[UV_RN];
    #pragma unroll
    for (int n = 0; n < UV_RN; ++n) { au[n] = 0.f; av[n] = 0.f; }
    if (t < F3) {
        const int g = t / 3, c = t - g * 3;
        for (int f = 0; f < FF; ++f) {
            const float wuv = wu[f * FF + g];
            const float wvv = wv[f * FF + g];
            const int kk = f * 3 + c;
            #pragma unroll
            for (int n = 0; n < UV_RN; ++n) {
                const float x = sV[n][kk];        // 3 distinct addrs -> broadcast
                au[n] = fmaf(x, wuv, au[n]);
                av[n] = fmaf(x, wvv, av[n]);
            }
        }
        #pragma unroll
        for (int n = 0; n < UV_RN; ++n)
            u_v[(size_t)(n0 + n) * F3 + t] = au[n];
    }
    __syncthreads();
    if (t < F3) {
        #pragma unroll
        for (int n = 0; n < UV_RN; ++n) sV[n][t] = av[n];   // phase 2: v values
    }
    __syncthreads();
    for (int idx = t; idx < FF * UV_RN; idx += 256) {
        int n = idx / FF, g = idx - n * FF;   // g fast -> coalesced vnorm write
        float a = sV[n][3*g], b = sV[n][3*g+1], c = sV[n][3*g+2];
        vnorm[(size_t)(n0 + n) * FF + g] = sqrtf(a * a + b * b + c * c + EPS_F);
    }
    __syncthreads();
    if (t < F3) {
        #pragma unroll
        for (int n = 0; n < UV_RN; ++n) sV[n][t] = au[n] * av[n];   // phase 3: u*v
    }
    __syncthreads();
    for (int idx = t; idx < FF * UV_RN; idx += 256) {
        int n = idx / FF, g = idx - n * FF;
        dotb[(size_t)(n0 + n) * FF + g] = sV[n][3*g] + sV[n][3*g+1] + sV[n][3*g+2];
    }
}

extern "C" void kernel_launch(void* const* d_in, const int* in_sizes, int n_in,
                              void* d_out, int out_size, void* d_ws, size_t ws_size,
                              hipStream_t stream)
{
    const float* xyz    = (const float*)d_in[0];
    const int*   nbr    = (const int*)  d_in[1];
    const float* Hin    = (const float*)d_in[3];
    const float* msg_w1 = (const float*)d_in[4];
    const float* msg_b1 = (const float*)d_in[5];
    const float* msg_w2 = (const float*)d_in[6];
    const float* msg_b2 = (const float*)d_in[7];
    const float* rbf_w  = (const float*)d_in[8];
    const float* rbf_b  = (const float*)d_in[9];
    const float* upd_wu = (const float*)d_in[10];
    const float* upd_wv = (const float*)d_in[11];
    const float* upd_w1 = (const float*)d_in[12];
    const float* upd_b1 = (const float*)d_in[13];
    const float* upd_w2 = (const float*)d_in[14];
    const float* upd_b2 = (const float*)d_in[15];
    const float* dw1    = (const float*)d_in[16];
    const float* db1    = (const float*)d_in[17];
    const float* dw2    = (const float*)d_in[18];
    const float* db2    = (const float*)d_in[19];
    const int E = in_sizes[1] / 2;
    const int ECAP = E / 2 + E / 25;   // active edges deterministic ~47%; cap 54%

    float* ws = (float*)d_ws;
    size_t off = 0;
    float* Hcur  = ws + off; off += (size_t)N_NODES * FF;
    float* VA    = ws + off; off += (size_t)N_NODES * F3;
    float* VB    = ws + off; off += (size_t)N_NODES * F3;
    __hip_bfloat16* phi = (__hip_bfloat16*)(ws + off); off += (size_t)N_NODES * F4 / 2;  // bf16
    __hip_bfloat16* Vbf = (__hip_bfloat16*)(ws + off); off += (size_t)N_NODES * F4 / 2;  // bf16x4 rows
    float* u_v   = ws + off; off += (size_t)N_NODES * F3;
    float* dotb  = ws + off; off += (size_t)N_NODES * FF;
    float* vnorm = ws + off; off += (size_t)N_NODES * FF;
    float* rec   = ws + off; off += (size_t)ECAP * REC_STRIDE;
    int* ibase     = (int*)(ws + off);
    int* row_start = ibase;                       // N+1
    int* counts    = row_start + (N_NODES + 1);   // N
    int* cursor    = counts + N_NODES;            // N
    int* jl        = cursor + N_NODES;            // ECAP

    k_init<<<dim3((N_NODES + 255) / 256), dim3(256), 0, stream>>>(counts, cursor);
    k_geo<<<dim3((E + 255) / 256), dim3(256), 0, stream>>>(xyz, nbr, counts, E);
    k_scan<<<dim3(1), dim3(1024), 0, stream>>>(counts, row_start, N_NODES);
    k_fill<<<dim3((E + 255) / 256), dim3(256), 0, stream>>>(xyz, nbr, row_start, cursor, rec, jl, E);

    float* dout = (float*)d_out;
    float* Vold = VA;
    float* Vnew = VB;
    for (int l = 0; l < NL; ++l) {
        // phi = silu(H@w1+b1)@w2+b2  (fused, bf16 out); layer 0 reads Hin directly
        const float* Hsrc = (l == 0) ? Hin : Hcur;
        k_mlp2<78, 0, 312, 4, 1><<<dim3(625), dim3(78, 4), 0, stream>>>(
            Hsrc, nullptr, msg_w1 + (size_t)l * 78 * 78, msg_b1 + (size_t)l * 78,
            msg_w2 + (size_t)l * 78 * 312, msg_b2 + (size_t)l * 312, phi, N_NODES);
        // message pass
        if (l == 0)
            k_message_l0<<<dim3(N_NODES), dim3(192), 0, stream>>>(
                phi, Hin, Vnew, Hcur, rec, jl, row_start,
                rbf_w + (size_t)l * NRBF * F4, rbf_b + (size_t)l * F4);
        else
            k_message<<<dim3(N_NODES), dim3(320), 0, stream>>>(
                phi, Vold, Vbf, Vnew, Hcur, rec, jl, row_start,
                rbf_w + (size_t)l * NRBF * F4, rbf_b + (size_t)l * F4);
        // u_v, dot(u,v), v_norm
        k_upd_uv<<<dim3(N_NODES / UV_RN), dim3(256), 0, stream>>>(
            Vnew, upd_wu + (size_t)l * 78 * 78, upd_wv + (size_t)l * 78 * 78, u_v, dotb, vnorm);
        // fused: a = silu([H|vnorm]@uw1+ub1)@uw2+ub2 ; apply to H,V ; (+decoder when last)
        if (l == NL - 1)
            k_updmlp_apply<1><<<dim3(625), dim3(78, 4), 0, stream>>>(
                Hcur, vnorm, upd_w1 + (size_t)l * 156 * 78, upd_b1 + (size_t)l * 78,
                upd_w2 + (size_t)l * 78 * 234, upd_b2 + (size_t)l * 234,
                u_v, dotb, Vnew, Vbf, dout,
                dw1, db1, dw2, db2, dout + (size_t)N_NODES * FF);
        else
            k_updmlp_apply<0><<<dim3(625), dim3(78, 4), 0, stream>>>(
                Hcur, vnorm, upd_w1 + (size_t)l * 156 * 78, upd_b1 + (size_t)l * 78,
                upd_w2 + (size_t)l * 78 * 234, upd_b2 + (size_t)l * 234,
                u_v, dotb, Vnew, Vbf, Hcur,
                dw1, db1, dw2, db2, nullptr);
        float* tmp = Vold; Vold = Vnew; Vnew = tmp;
    }
}